// Round 1
// baseline (605.831 us; speedup 1.0000x reference)
//
#include <hip/hip_runtime.h>

// LSTM: B=8192, T=512, IN=5, H=32 (4H=128 gates), head 32->1 on last h.
// One thread per (batch, hidden j). W_hh gate rows live in VGPRs.
// h double-buffered in LDS, one barrier per timestep. 2 batch elems / 64-thread block.

static constexpr int BB  = 8192;
static constexpr int TT  = 512;
static constexpr int NIN = 5;
static constexpr int HH  = 32;

__device__ __forceinline__ float fast_sigmoid(float x) {
    // 1 / (1 + 2^(-x*log2(e)))  — saturates correctly at +/-inf
    float e = __builtin_amdgcn_exp2f(-1.4426950408889634f * x);
    return __builtin_amdgcn_rcpf(1.0f + e);
}

__device__ __forceinline__ float fast_tanh(float x) {
    // 1 - 2 / (1 + 2^(2x*log2(e)))
    float e = __builtin_amdgcn_exp2f(2.8853900817779268f * x);
    return 1.0f - 2.0f * __builtin_amdgcn_rcpf(1.0f + e);
}

__global__ __launch_bounds__(64, 2) void lstm_fused(
    const float* __restrict__ x,     // [B, T, 5]
    const float* __restrict__ W_ih,  // [128, 5]
    const float* __restrict__ W_hh,  // [128, 32]
    const float* __restrict__ b_ih,  // [128]
    const float* __restrict__ b_hh,  // [128]
    const float* __restrict__ W_fc,  // [1, 32]
    const float* __restrict__ b_fc,  // [1]
    float* __restrict__ out)         // [B, 1]
{
    const int tid = threadIdx.x;   // 0..63
    const int bl  = tid >> 5;      // local batch 0..1
    const int j   = tid & 31;      // hidden index
    const int b   = blockIdx.x * 2 + bl;

    __shared__ __align__(16) float h_lds[2][2][HH];  // [buf][bl][j]

    // ---- per-thread weights in registers ----
    float wi[HH], wf[HH], wg[HH], wo[HH];
    {
        const float4* r0 = reinterpret_cast<const float4*>(W_hh + (0 * HH + j) * HH);
        const float4* r1 = reinterpret_cast<const float4*>(W_hh + (1 * HH + j) * HH);
        const float4* r2 = reinterpret_cast<const float4*>(W_hh + (2 * HH + j) * HH);
        const float4* r3 = reinterpret_cast<const float4*>(W_hh + (3 * HH + j) * HH);
#pragma unroll
        for (int q = 0; q < HH / 4; ++q) {
            float4 a = r0[q]; wi[4*q+0]=a.x; wi[4*q+1]=a.y; wi[4*q+2]=a.z; wi[4*q+3]=a.w;
            float4 f = r1[q]; wf[4*q+0]=f.x; wf[4*q+1]=f.y; wf[4*q+2]=f.z; wf[4*q+3]=f.w;
            float4 g = r2[q]; wg[4*q+0]=g.x; wg[4*q+1]=g.y; wg[4*q+2]=g.z; wg[4*q+3]=g.w;
            float4 o = r3[q]; wo[4*q+0]=o.x; wo[4*q+1]=o.y; wo[4*q+2]=o.z; wo[4*q+3]=o.w;
        }
    }
    float wxi[NIN], wxf[NIN], wxg[NIN], wxo[NIN];
#pragma unroll
    for (int i = 0; i < NIN; ++i) {
        wxi[i] = W_ih[(0 * HH + j) * NIN + i];
        wxf[i] = W_ih[(1 * HH + j) * NIN + i];
        wxg[i] = W_ih[(2 * HH + j) * NIN + i];
        wxo[i] = W_ih[(3 * HH + j) * NIN + i];
    }
    const float bi = b_ih[0 * HH + j] + b_hh[0 * HH + j];
    const float bf = b_ih[1 * HH + j] + b_hh[1 * HH + j];
    const float bg = b_ih[2 * HH + j] + b_hh[2 * HH + j];
    const float bo = b_ih[3 * HH + j] + b_hh[3 * HH + j];

    float c = 0.0f, h = 0.0f;
    h_lds[0][bl][j] = 0.0f;
    __syncthreads();

    const float* xb = x + (size_t)b * (TT * NIN);

#pragma unroll 1
    for (int t = 0; t < TT; ++t) {
        const int cur = t & 1;
        const int nxt = cur ^ 1;

        // x for this step (5 floats, broadcast across the 32-lane group; L1-resident)
        const float* xp = xb + t * NIN;
        const float x0 = xp[0], x1 = xp[1], x2 = xp[2], x3 = xp[3], x4 = xp[4];

        float acc_i = bi, acc_f = bf, acc_g = bg, acc_o = bo;

        // h . W_hh  (broadcast float4 reads from LDS, conflict-free)
        const float4* h4 = reinterpret_cast<const float4*>(h_lds[cur][bl]);
#pragma unroll
        for (int q = 0; q < HH / 4; ++q) {
            const float4 hv = h4[q];
            acc_i = fmaf(wi[4*q+0], hv.x, acc_i);
            acc_i = fmaf(wi[4*q+1], hv.y, acc_i);
            acc_i = fmaf(wi[4*q+2], hv.z, acc_i);
            acc_i = fmaf(wi[4*q+3], hv.w, acc_i);
            acc_f = fmaf(wf[4*q+0], hv.x, acc_f);
            acc_f = fmaf(wf[4*q+1], hv.y, acc_f);
            acc_f = fmaf(wf[4*q+2], hv.z, acc_f);
            acc_f = fmaf(wf[4*q+3], hv.w, acc_f);
            acc_g = fmaf(wg[4*q+0], hv.x, acc_g);
            acc_g = fmaf(wg[4*q+1], hv.y, acc_g);
            acc_g = fmaf(wg[4*q+2], hv.z, acc_g);
            acc_g = fmaf(wg[4*q+3], hv.w, acc_g);
            acc_o = fmaf(wo[4*q+0], hv.x, acc_o);
            acc_o = fmaf(wo[4*q+1], hv.y, acc_o);
            acc_o = fmaf(wo[4*q+2], hv.z, acc_o);
            acc_o = fmaf(wo[4*q+3], hv.w, acc_o);
        }

        // x projection (20 FMA)
        acc_i = fmaf(wxi[0], x0, acc_i); acc_i = fmaf(wxi[1], x1, acc_i);
        acc_i = fmaf(wxi[2], x2, acc_i); acc_i = fmaf(wxi[3], x3, acc_i);
        acc_i = fmaf(wxi[4], x4, acc_i);
        acc_f = fmaf(wxf[0], x0, acc_f); acc_f = fmaf(wxf[1], x1, acc_f);
        acc_f = fmaf(wxf[2], x2, acc_f); acc_f = fmaf(wxf[3], x3, acc_f);
        acc_f = fmaf(wxf[4], x4, acc_f);
        acc_g = fmaf(wxg[0], x0, acc_g); acc_g = fmaf(wxg[1], x1, acc_g);
        acc_g = fmaf(wxg[2], x2, acc_g); acc_g = fmaf(wxg[3], x3, acc_g);
        acc_g = fmaf(wxg[4], x4, acc_g);
        acc_o = fmaf(wxo[0], x0, acc_o); acc_o = fmaf(wxo[1], x1, acc_o);
        acc_o = fmaf(wxo[2], x2, acc_o); acc_o = fmaf(wxo[3], x3, acc_o);
        acc_o = fmaf(wxo[4], x4, acc_o);

        const float iv = fast_sigmoid(acc_i);
        const float fv = fast_sigmoid(acc_f);
        const float gv = fast_tanh(acc_g);
        const float ov = fast_sigmoid(acc_o);

        c = fmaf(fv, c, iv * gv);
        h = ov * fast_tanh(c);

        h_lds[nxt][bl][j] = h;   // write other buffer; no race with cur readers
        __syncthreads();         // nxt visible before next step reads it
    }

    // head: out[b] = sum_j h[b,j] * W_fc[0,j] + b_fc[0]
    float v = h * W_fc[j];
    v += __shfl_xor(v, 16);
    v += __shfl_xor(v, 8);
    v += __shfl_xor(v, 4);
    v += __shfl_xor(v, 2);
    v += __shfl_xor(v, 1);
    if (j == 0) out[b] = v + b_fc[0];
}

extern "C" void kernel_launch(void* const* d_in, const int* in_sizes, int n_in,
                              void* d_out, int out_size, void* d_ws, size_t ws_size,
                              hipStream_t stream) {
    const float* x    = (const float*)d_in[0];
    const float* W_ih = (const float*)d_in[1];
    const float* W_hh = (const float*)d_in[2];
    const float* b_ih = (const float*)d_in[3];
    const float* b_hh = (const float*)d_in[4];
    const float* W_fc = (const float*)d_in[5];
    const float* b_fc = (const float*)d_in[6];
    float* out = (float*)d_out;

    lstm_fused<<<dim3(BB / 2), dim3(64), 0, stream>>>(
        x, W_ih, W_hh, b_ih, b_hh, W_fc, b_fc, out);
}

// Round 2
// 334.979 us; speedup vs baseline: 1.8086x; 1.8086x over previous
//
#include <hip/hip_runtime.h>

// LSTM via MFMA: B=8192, T=512, IN=5, H=32.
// Group = 16 batches, 4 waves/group. gates[16b x 128] = hext[16 x 64] * Wext^T via
// mfma_f32_16x16x32_bf16. n-tile t = gate t for 16 j's -> each lane holds i,f,g,o
// for its (batch,j) cells in acc regs; c persistent in VGPRs; h via swizzled LDS.
// Precision: W_hh split hi/lo bf16; x_lo, W_ih_lo, bias_lo packed into spare K slots.

typedef __attribute__((ext_vector_type(8))) short short8;
typedef __attribute__((ext_vector_type(4))) float f32x4;

static constexpr int BB  = 8192;
static constexpr int TT  = 512;
static constexpr int NIN = 5;
static constexpr int HH  = 32;

__device__ __forceinline__ unsigned short bf_rne(float f) {
    unsigned int u = __float_as_uint(f);
    u = (u + 0x7FFFu + ((u >> 16) & 1u)) >> 16;
    return (unsigned short)u;
}
__device__ __forceinline__ float bf_f32(unsigned short h) {
    return __uint_as_float((unsigned int)h << 16);
}
__device__ __forceinline__ float fast_sigmoid(float x) {
    float e = __builtin_amdgcn_exp2f(-1.4426950408889634f * x);
    return __builtin_amdgcn_rcpf(1.0f + e);
}
__device__ __forceinline__ float fast_tanh(float x) {
    float e = __builtin_amdgcn_exp2f(2.8853900817779268f * x);
    return 1.0f - 2.0f * __builtin_amdgcn_rcpf(1.0f + e);
}

__global__ __launch_bounds__(256, 2) void lstm_mfma(
    const float* __restrict__ x,     // [B, T, 5]
    const float* __restrict__ W_ih,  // [128, 5]
    const float* __restrict__ W_hh,  // [128, 32]
    const float* __restrict__ b_ih,  // [128]
    const float* __restrict__ b_hh,  // [128]
    const float* __restrict__ W_fc,  // [1, 32]
    const float* __restrict__ b_fc,  // [1]
    float* __restrict__ out)         // [B]
{
    const int tid  = threadIdx.x;
    const int lane = tid & 63;
    const int w    = tid >> 6;   // wave 0..3
    const int jh   = w >> 1;     // j half: j in [16*jh, 16*jh+16)
    const int rh   = w & 1;      // row half: this wave updates acc rows {2rh, 2rh+1}
    const int col  = lane & 15;
    const int kg   = lane >> 4;  // k-group 0..3
    const int b0   = blockIdx.x * 16;

    // h tile: 16 rows x 128 B (only k<32 logically used; XOR swizzle spreads banks)
    __shared__ __align__(16) unsigned char hb[2][16 * 128];
    __shared__ float parts[32];

    {   // zero both h buffers (h0 = 0)
        unsigned int* p = (unsigned int*)&hb[0][0];
#pragma unroll
        for (int q = 0; q < 4; ++q) p[tid + q * 256] = 0u;
    }

    // ---- B fragments (per wave, registers, built once) ----
    // b tile t: rows r = t*32 + jh*16 + n (n = col), k = kg*8 + e
    short8 bhi[4], blo[4], b1[4];
#pragma unroll
    for (int t4 = 0; t4 < 4; ++t4) {
        const int r = t4 * 32 + jh * 16 + col;
#pragma unroll
        for (int e = 0; e < 8; ++e) {
            float wv = W_hh[r * HH + kg * 8 + e];
            unsigned short hh = bf_rne(wv);
            bhi[t4][e] = (short)hh;
            blo[t4][e] = (short)bf_rne(wv - bf_f32(hh));
        }
        float bias = b_ih[r] + b_hh[r];
        unsigned short bh = bf_rne(bias);
        unsigned short bl = bf_rne(bias - bf_f32(bh));
        short8 v;
#pragma unroll
        for (int e = 0; e < 8; ++e) v[e] = 0;
        if (kg == 0 || kg == 1) {
            // pairs a1 = x_hi (kg0) / x_lo (kg1): both times W_ih high part
#pragma unroll
            for (int e = 0; e < NIN; ++e) v[e] = (short)bf_rne(W_ih[r * NIN + e]);
            v[5] = (short)((kg == 0) ? bh : bl);   // pairs a1[5]=1.0
        } else if (kg == 2) {
            // pairs a1 = x_hi again: W_ih low part
#pragma unroll
            for (int e = 0; e < NIN; ++e) {
                float wv = W_ih[r * NIN + e];
                unsigned short h2 = bf_rne(wv);
                v[e] = (short)bf_rne(wv - bf_f32(h2));
            }
        }
        b1[t4] = v;
    }

    __syncthreads();  // h zeros visible

    // ---- x stream: lane handles batch b0+col (redundant across kg/waves, L1-hit) ----
    const float* xb = x + (size_t)(b0 + col) * (TT * NIN);
    float xc[NIN];
#pragma unroll
    for (int e = 0; e < NIN; ++e) xc[e] = xb[e];

    float c0 = 0.f, c1 = 0.f, h0f = 0.f, h1f = 0.f;

#pragma unroll 2
    for (int t = 0; t < TT; ++t) {
        const int cur = t & 1, nxt = cur ^ 1;

        // prefetch next step's x
        const int tn = (t + 1 < TT) ? (t + 1) : t;
        float xn[NIN];
#pragma unroll
        for (int e = 0; e < NIN; ++e) xn[e] = xb[tn * NIN + e];

        // A0: h fragment from LDS. row m = col, k = kg*8..+7. swizzled.
        const unsigned int ro = ((unsigned)(kg * 16)) ^ (((unsigned)(col & 7)) << 4);
        short8 a0 = *(const short8*)&hb[cur][col * 128 + ro];

        // A1: x/bias fragment in registers. k-slice by kg:
        //  kg0: x_hi[0..4], 1.0 ; kg1: x_lo[0..4], 1.0 ; kg2: x_hi[0..4] ; kg3: 0
        unsigned short xh[NIN], xl[NIN];
#pragma unroll
        for (int e = 0; e < NIN; ++e) {
            unsigned short h = bf_rne(xc[e]);
            xh[e] = h;
            xl[e] = bf_rne(xc[e] - bf_f32(h));
        }
        short8 a1;
#pragma unroll
        for (int e = 0; e < NIN; ++e) {
            unsigned short s = (kg == 1) ? xl[e] : xh[e];
            a1[e] = (kg == 3) ? (short)0 : (short)s;
        }
        a1[5] = (kg < 2) ? (short)0x3F80 : (short)0;  // 1.0 pairs bias hi/lo
        a1[6] = 0; a1[7] = 0;

        // gates: acc_t[reg] = gate_t[batch=(lane>>4)*4+reg][j=jh*16+col]
        const f32x4 z = {0.f, 0.f, 0.f, 0.f};
        f32x4 ai = __builtin_amdgcn_mfma_f32_16x16x32_bf16(a0, blo[0], z, 0, 0, 0);
        ai = __builtin_amdgcn_mfma_f32_16x16x32_bf16(a0, bhi[0], ai, 0, 0, 0);
        ai = __builtin_amdgcn_mfma_f32_16x16x32_bf16(a1, b1[0],  ai, 0, 0, 0);
        f32x4 af = __builtin_amdgcn_mfma_f32_16x16x32_bf16(a0, blo[1], z, 0, 0, 0);
        af = __builtin_amdgcn_mfma_f32_16x16x32_bf16(a0, bhi[1], af, 0, 0, 0);
        af = __builtin_amdgcn_mfma_f32_16x16x32_bf16(a1, b1[1],  af, 0, 0, 0);
        f32x4 ag = __builtin_amdgcn_mfma_f32_16x16x32_bf16(a0, blo[2], z, 0, 0, 0);
        ag = __builtin_amdgcn_mfma_f32_16x16x32_bf16(a0, bhi[2], ag, 0, 0, 0);
        ag = __builtin_amdgcn_mfma_f32_16x16x32_bf16(a1, b1[2],  ag, 0, 0, 0);
        f32x4 ao = __builtin_amdgcn_mfma_f32_16x16x32_bf16(a0, blo[3], z, 0, 0, 0);
        ao = __builtin_amdgcn_mfma_f32_16x16x32_bf16(a0, bhi[3], ao, 0, 0, 0);
        ao = __builtin_amdgcn_mfma_f32_16x16x32_bf16(a1, b1[3],  ao, 0, 0, 0);

        // cell updates: this wave owns acc rows {2rh, 2rh+1} -> batches kg*4+2rh+rr
        const int j = jh * 16 + col;
        {
            float iv = fast_sigmoid(rh ? ai[2] : ai[0]);
            float fv = fast_sigmoid(rh ? af[2] : af[0]);
            float gv = fast_tanh   (rh ? ag[2] : ag[0]);
            float ov = fast_sigmoid(rh ? ao[2] : ao[0]);
            c0 = fv * c0 + iv * gv;
            h0f = ov * fast_tanh(c0);
            const int m = kg * 4 + rh * 2 + 0;
            const unsigned int off = ((unsigned)(j * 2)) ^ (((unsigned)(m & 7)) << 4);
            *(unsigned short*)&hb[nxt][m * 128 + off] = bf_rne(h0f);
        }
        {
            float iv = fast_sigmoid(rh ? ai[3] : ai[1]);
            float fv = fast_sigmoid(rh ? af[3] : af[1]);
            float gv = fast_tanh   (rh ? ag[3] : ag[1]);
            float ov = fast_sigmoid(rh ? ao[3] : ao[1]);
            c1 = fv * c1 + iv * gv;
            h1f = ov * fast_tanh(c1);
            const int m = kg * 4 + rh * 2 + 1;
            const unsigned int off = ((unsigned)(j * 2)) ^ (((unsigned)(m & 7)) << 4);
            *(unsigned short*)&hb[nxt][m * 128 + off] = bf_rne(h1f);
        }

#pragma unroll
        for (int e = 0; e < NIN; ++e) xc[e] = xn[e];

        __syncthreads();  // h(t+1) visible; all reads of hb[cur] done
    }

    // ---- head: out[b] = sum_j h[b][j] * W_fc[j] + b_fc ----
    const int j = jh * 16 + col;
    const float wfc = W_fc[j];
    float v0 = h0f * wfc, v1 = h1f * wfc;
    v0 += __shfl_xor(v0, 1); v0 += __shfl_xor(v0, 2);
    v0 += __shfl_xor(v0, 4); v0 += __shfl_xor(v0, 8);
    v1 += __shfl_xor(v1, 1); v1 += __shfl_xor(v1, 2);
    v1 += __shfl_xor(v1, 4); v1 += __shfl_xor(v1, 8);
    if (col == 0) {
        parts[jh * 16 + kg * 4 + rh * 2 + 0] = v0;
        parts[jh * 16 + kg * 4 + rh * 2 + 1] = v1;
    }
    __syncthreads();
    if (tid < 16) out[b0 + tid] = parts[tid] + parts[16 + tid] + b_fc[0];
}

extern "C" void kernel_launch(void* const* d_in, const int* in_sizes, int n_in,
                              void* d_out, int out_size, void* d_ws, size_t ws_size,
                              hipStream_t stream) {
    const float* x    = (const float*)d_in[0];
    const float* W_ih = (const float*)d_in[1];
    const float* W_hh = (const float*)d_in[2];
    const float* b_ih = (const float*)d_in[3];
    const float* b_hh = (const float*)d_in[4];
    const float* W_fc = (const float*)d_in[5];
    const float* b_fc = (const float*)d_in[6];
    float* out = (float*)d_out;

    lstm_mfma<<<dim3(BB / 16), dim3(256), 0, stream>>>(
        x, W_ih, W_hh, b_ih, b_hh, W_fc, b_fc, out);
}